// Round 7
// baseline (444.786 us; speedup 1.0000x reference)
//
#include <hip/hip_runtime.h>

// FourierFeatureMLP fused kernel for MI355X (gfx950). Round 7.
//
// Diagnosis after r4/r5/r6 (all ~290 us, MfmaUtil 20%, VALUBusy 30%):
// pipes run SERIALLY - K-loop (matrix) and tanh epilogue (VALU) are
// barrier-separated phases and all resident waves stay phase-locked, so
// matrix+VALU+LDS+mem utilizations SUM to ~90% instead of overlapping.
//
// Fix: dual-tile interleave. Block owns two 64-point tiles A,B. Per layer:
//   P1: K-loop(A) with epilogue(B, prev layer) interleaved per K-step
//   P2: K-loop(B) with epilogue(A, this layer) interleaved
// The epi VALU ops are independent of the in-flight MFMAs -> single-wave
// matrix/VALU overlap in every phase. 2 barriers/layer as before.
//
// Layouts (MFMA 16x16x32, learn_hip-verified):
//   A: lane holds A[m=lane&15][k=quad*8+j]  -> W[o][k] row o = base+laneM
//   B: lane holds B[k=quad*8+j][n=lane&15]  -> h[pt=base+laneM][k..k+7]
//   D: n(point)=lane&15, m(hidden unit)=quad*4+reg -> 4 consecutive units.
// hbuf swizzle: 16B chunk' = chunk ^ (row&7).

#define HDIM   256
#define NFREQ  128
#define NLAYER 8
#define TILE_N 64          // per sub-tile; block covers 128 points
#define NTHR   256
#define WELTS  (NLAYER * HDIM * HDIM)

typedef __attribute__((ext_vector_type(8))) _Float16 half8;
typedef __attribute__((ext_vector_type(4))) _Float16 half4;
typedef __attribute__((ext_vector_type(2))) _Float16 half2;
typedef __attribute__((ext_vector_type(4))) float float4v;

__device__ __forceinline__ half2 pk2(float a, float b) {
    return __builtin_bit_cast(half2, __builtin_amdgcn_cvt_pkrtz(a, b));
}

// tanh(acc + b) with pre-scaled bias bK = b * 2/ln2. Saturation-safe.
#define TANH_K 2.885390081777927f
__device__ __forceinline__ float fast_tanh_fused(float acc, float bK) {
    float z = __builtin_amdgcn_exp2f(fmaf(acc, TANH_K, bK));
    float r = __builtin_amdgcn_rcpf(z + 1.0f);
    return fmaf(-2.0f, r, 1.0f);
}

__device__ __forceinline__ int swz(int row, int k) {
    return row * HDIM + ((((k >> 3) ^ (row & 7)) << 3) | (k & 7));
}

// ---- pre-pass: fp32 -> fp16 weights into d_ws (layer 0 = W_in, 1..7 = W_h)
__global__ void convert_w_kernel(const float* __restrict__ W_in,
                                 const float* __restrict__ W_h,
                                 _Float16* __restrict__ dst)
{
    const int i = blockIdx.x * blockDim.x + threadIdx.x;
    const float v = (i < HDIM * HDIM) ? W_in[i] : W_h[i - HDIM * HDIM];
    dst[i] = (_Float16)v;
}

// One phase: K-loop over rbuf (accumulating accK) with, if EPI, the
// epilogue of the OTHER tile (accE -> tanh -> ebuf) interleaved
// 2 fragment-groups per K-step (8 steps x 2 = all 16 groups).
template<bool EPI>
__device__ __forceinline__ void dense_phase(
    const _Float16* __restrict__ Wl,
    const _Float16* __restrict__ rbuf,
    _Float16* __restrict__ ebuf,
    const float* __restrict__ blE,        // bias (fp32) for the epi tile
    float4v (&accK)[4][4], float4v (&accE)[4][4],
    const int nQ, const int laneM, const int quad)
{
    half8 a[2][4], b[2][4];

    // preload K-step 0
    #pragma unroll
    for (int at = 0; at < 4; ++at) {
        const int o = nQ * 64 + at * 16 + laneM;
        a[0][at] = *(const half8*)&Wl[o * HDIM + quad * 8];
    }
    #pragma unroll
    for (int pt = 0; pt < 4; ++pt) {
        const int m = pt * 16 + laneM;
        b[0][pt] = *(const half8*)&rbuf[m * HDIM + ((quad ^ (m & 7)) << 3)];
    }
    #pragma unroll
    for (int at = 0; at < 4; ++at)
        #pragma unroll
        for (int pt = 0; pt < 4; ++pt)
            accK[at][pt] = (float4v){0.f, 0.f, 0.f, 0.f};

    // pre-scaled biases for the epi tile (one float4 per 'at' group)
    float4 bK[4];
    if (EPI) {
        #pragma unroll
        for (int at = 0; at < 4; ++at) {
            float4 t = *(const float4*)&blE[nQ * 64 + at * 16 + quad * 4];
            t.x *= TANH_K; t.y *= TANH_K; t.z *= TANH_K; t.w *= TANH_K;
            bK[at] = t;
        }
    }

    #pragma unroll
    for (int ks = 0; ks < 8; ++ks) {
        const int cur = ks & 1, nxt = cur ^ 1;
        if (ks < 7) {
            const int kk = (ks + 1) * 32 + quad * 8;
            #pragma unroll
            for (int at = 0; at < 4; ++at) {
                const int o = nQ * 64 + at * 16 + laneM;
                a[nxt][at] = *(const half8*)&Wl[o * HDIM + kk];
            }
            #pragma unroll
            for (int pt = 0; pt < 4; ++pt) {
                const int m = pt * 16 + laneM;
                b[nxt][pt] = *(const half8*)&rbuf[m * HDIM + (((kk >> 3) ^ (m & 7)) << 3)];
            }
        }
        #pragma unroll
        for (int at = 0; at < 4; ++at)
            #pragma unroll
            for (int pt = 0; pt < 4; ++pt)
                accK[at][pt] = __builtin_amdgcn_mfma_f32_16x16x32_f16(
                    a[cur][at], b[cur][pt], accK[at][pt], 0, 0, 0);

        if (EPI) {
            // 2 epilogue groups in the shadow of the 16 MFMAs above
            #pragma unroll
            for (int gi = 0; gi < 2; ++gi) {
                const int g  = 2 * ks + gi;
                const int at = g >> 2, pt = g & 3;
                const int u0 = nQ * 64 + at * 16 + quad * 4;
                const int m  = pt * 16 + laneM;
                const float4v e = accE[at][pt];
                const float v0 = fast_tanh_fused(e.x, bK[at].x);
                const float v1 = fast_tanh_fused(e.y, bK[at].y);
                const float v2 = fast_tanh_fused(e.z, bK[at].z);
                const float v3 = fast_tanh_fused(e.w, bK[at].w);
                const half2 lo = pk2(v0, v1);
                const half2 hi = pk2(v2, v3);
                half4 pkv;
                pkv.x = lo.x; pkv.y = lo.y; pkv.z = hi.x; pkv.w = hi.y;
                *(half4*)&ebuf[swz(m, u0)] = pkv;     // ds_write_b64
            }
        }
    }
}

// standalone epilogue (for tile B after the last layer)
__device__ __forceinline__ void epi_all(
    float4v (&accE)[4][4], const float* __restrict__ blE,
    _Float16* __restrict__ ebuf,
    const int nQ, const int laneM, const int quad)
{
    #pragma unroll
    for (int at = 0; at < 4; ++at) {
        const int u0 = nQ * 64 + at * 16 + quad * 4;
        float4 b4 = *(const float4*)&blE[u0];
        b4.x *= TANH_K; b4.y *= TANH_K; b4.z *= TANH_K; b4.w *= TANH_K;
        #pragma unroll
        for (int pt = 0; pt < 4; ++pt) {
            const int m = pt * 16 + laneM;
            const float4v e = accE[at][pt];
            const float v0 = fast_tanh_fused(e.x, b4.x);
            const float v1 = fast_tanh_fused(e.y, b4.y);
            const float v2 = fast_tanh_fused(e.z, b4.z);
            const float v3 = fast_tanh_fused(e.w, b4.w);
            const half2 lo = pk2(v0, v1);
            const half2 hi = pk2(v2, v3);
            half4 pkv;
            pkv.x = lo.x; pkv.y = lo.y; pkv.z = hi.x; pkv.w = hi.y;
            *(half4*)&ebuf[swz(m, u0)] = pkv;
        }
    }
}

__global__ __launch_bounds__(NTHR, 2)
void ffmlp_kernel(const float* __restrict__ tx,
                  const float* __restrict__ Bf,
                  const _Float16* __restrict__ Wall,
                  const float* __restrict__ b_in,
                  const float* __restrict__ b_h,
                  const float* __restrict__ W_out,
                  const float* __restrict__ b_out,
                  float* __restrict__ out)
{
    __shared__ __align__(16) _Float16 hbufA[TILE_N * HDIM];  // 32 KB
    __shared__ __align__(16) _Float16 hbufB[TILE_N * HDIM];  // 32 KB

    const int tid  = threadIdx.x;
    const int row0 = blockIdx.x * (2 * TILE_N);   // block covers 128 points
    const int lane = tid & 63;
    const int wave = tid >> 6;            // 0..3
    const int nQ    = wave;               // hidden-unit quarter
    const int laneM = lane & 15;
    const int quad  = lane >> 4;

    // ---------------- stage 1: Fourier features -> hbufA (rows 0-63), hbufB
    {
        const float2* txv = (const float2*)tx;
        const float4 Bp = *(const float4*)&Bf[4 * lane];   // freq pair
        const int f0 = 2 * lane;
        #pragma unroll 4
        for (int i = 0; i < 32; ++i) {
            const int row = wave * 32 + i;           // 0..127
            _Float16* hb = (row < TILE_N) ? hbufA : hbufB;
            const int lrow = row & (TILE_N - 1);
            const float2 t = txv[row0 + row];
            float r0 = t.x * Bp.x + t.y * Bp.y;      // revolutions
            float r1 = t.x * Bp.z + t.y * Bp.w;
            r0 = __builtin_amdgcn_fractf(r0);
            r1 = __builtin_amdgcn_fractf(r1);
            half2 sp = pk2(__builtin_amdgcn_sinf(r0), __builtin_amdgcn_sinf(r1));
            half2 cp = pk2(__builtin_amdgcn_cosf(r0), __builtin_amdgcn_cosf(r1));
            *(half2*)&hb[swz(lrow, f0)]         = sp;
            *(half2*)&hb[swz(lrow, f0 + NFREQ)] = cp;
        }
    }
    __syncthreads();

    // ---------------- stage 2: 8 layers, dual-tile interleaved ----------------
    float4v accA[4][4], accB[4][4];
    const float* bl_prev = nullptr;

    for (int layer = 0; layer < NLAYER; ++layer) {
        const _Float16* Wl = Wall + layer * (HDIM * HDIM);
        const float* bl = (layer == 0) ? b_in : b_h + (layer - 1) * HDIM;

        // P1: K(A, layer) + epi(B, layer-1)
        if (layer == 0)
            dense_phase<false>(Wl, hbufA, nullptr, nullptr, accA, accB,
                               nQ, laneM, quad);
        else
            dense_phase<true>(Wl, hbufA, hbufB, bl_prev, accA, accB,
                              nQ, laneM, quad);
        __syncthreads();

        // P2: K(B, layer) + epi(A, layer)
        dense_phase<true>(Wl, hbufB, hbufA, bl, accB, accA,
                          nQ, laneM, quad);
        __syncthreads();

        bl_prev = bl;
    }

    // tail: epilogue of B for the last layer
    epi_all(accB, bl_prev, hbufB, nQ, laneM, quad);
    __syncthreads();

    // ---------------- stage 3: output matvec for both tiles ----------------
    {
        const int row = tid >> 2;       // 0..63
        const int cq  = tid & 3;
        #pragma unroll
        for (int tb = 0; tb < 2; ++tb) {
            const _Float16* hb = tb ? hbufB : hbufA;
            float sum = 0.f;
            #pragma unroll
            for (int j = 0; j < 8; ++j) {
                const int c = cq * 8 + j;
                const half8 hv = *(const half8*)&hb[row * HDIM + ((c ^ (row & 7)) << 3)];
                const float4 w0 = *(const float4*)&W_out[c * 8];
                const float4 w1 = *(const float4*)&W_out[c * 8 + 4];
                sum += (float)hv[0] * w0.x + (float)hv[1] * w0.y +
                       (float)hv[2] * w0.z + (float)hv[3] * w0.w +
                       (float)hv[4] * w1.x + (float)hv[5] * w1.y +
                       (float)hv[6] * w1.z + (float)hv[7] * w1.w;
            }
            sum += __shfl_xor(sum, 1);
            sum += __shfl_xor(sum, 2);
            if (cq == 0)
                out[row0 + tb * TILE_N + row] = sum + b_out[0];
        }
    }
}

extern "C" void kernel_launch(void* const* d_in, const int* in_sizes, int n_in,
                              void* d_out, int out_size, void* d_ws, size_t ws_size,
                              hipStream_t stream) {
    const float* tx    = (const float*)d_in[0];
    const float* Bf    = (const float*)d_in[1];
    const float* W_in  = (const float*)d_in[2];
    const float* b_in  = (const float*)d_in[3];
    const float* W_h   = (const float*)d_in[4];
    const float* b_h   = (const float*)d_in[5];
    const float* W_out = (const float*)d_in[6];
    const float* b_out = (const float*)d_in[7];
    float* out = (float*)d_out;

    _Float16* Wall = (_Float16*)d_ws;   // 1 MiB scratch

    const int npts   = in_sizes[0] / 2;
    const int blocks = npts / (2 * TILE_N);   // 1024

    convert_w_kernel<<<WELTS / NTHR, NTHR, 0, stream>>>(W_in, W_h, Wall);
    ffmlp_kernel<<<blocks, NTHR, 0, stream>>>(tx, Bf, Wall, b_in, b_h,
                                              W_out, b_out, out);
}

// Round 8
// 425.378 us; speedup vs baseline: 1.0456x; 1.0456x over previous
//
#include <hip/hip_runtime.h>

// FourierFeatureMLP fused kernel for MI355X (gfx950). Round 8.
//
// r7 lesson: two live acc sets -> scratch spills (FETCH 157MB/WRITE 124MB).
// This round: fat wave with ONE live acc set. Wave tile = 64 units x 128
// points (acc[4][8] = 128 regs, AGPR-resident). Per K-step: 12 operand
// loads feed 32 MFMAs (~620 cyc matrix burst vs r6's 310) -> less exposed
// load latency per phase even with waves barrier-aligned.
// Swizzle upgraded to chunk ^ (m & 31) (full spread, rows have 32 chunks).
//
// Layouts (MFMA 16x16x32, learn_hip-verified):
//   A: lane holds A[m=lane&15][k=quad*8+j]  -> W[o][k] row o = base+laneM
//   B: lane holds B[k=quad*8+j][n=lane&15]  -> h[pt=base+laneM][k..k+7]
//   D: n(point)=lane&15, m(unit)=quad*4+reg -> 4 consecutive units.

#define HDIM   256
#define NFREQ  128
#define NLAYER 8
#define TILE_N 128         // points per block
#define NTHR   256         // 4 waves; wave = 64 units x 128 points
#define WELTS  (NLAYER * HDIM * HDIM)

typedef __attribute__((ext_vector_type(8))) _Float16 half8;
typedef __attribute__((ext_vector_type(4))) _Float16 half4;
typedef __attribute__((ext_vector_type(2))) _Float16 half2;
typedef __attribute__((ext_vector_type(4))) float float4v;

__device__ __forceinline__ half2 pk2(float a, float b) {
    return __builtin_bit_cast(half2, __builtin_amdgcn_cvt_pkrtz(a, b));
}

// tanh(acc + b) with pre-scaled bias bK = b * 2/ln2. Saturation-safe.
#define TANH_K 2.885390081777927f
__device__ __forceinline__ float fast_tanh_fused(float acc, float bK) {
    float z = __builtin_amdgcn_exp2f(fmaf(acc, TANH_K, bK));
    float r = __builtin_amdgcn_rcpf(z + 1.0f);
    return fmaf(-2.0f, r, 1.0f);
}

// swizzled LDS element index for h[row][k]; 32 x 16B chunks per row,
// chunk' = chunk ^ (row & 31): full-spread, b128-aligned.
__device__ __forceinline__ int swz(int row, int k) {
    return row * HDIM + ((((k >> 3) ^ (row & 31)) << 3) | (k & 7));
}

// ---- pre-pass: fp32 -> fp16 weights into d_ws (layer 0 = W_in, 1..7 = W_h)
__global__ void convert_w_kernel(const float* __restrict__ W_in,
                                 const float* __restrict__ W_h,
                                 _Float16* __restrict__ dst)
{
    const int i = blockIdx.x * blockDim.x + threadIdx.x;
    const float v = (i < HDIM * HDIM) ? W_in[i] : W_h[i - HDIM * HDIM];
    dst[i] = (_Float16)v;
}

__global__ __launch_bounds__(NTHR, 2)
void ffmlp_kernel(const float* __restrict__ tx,
                  const float* __restrict__ Bf,
                  const _Float16* __restrict__ Wall,
                  const float* __restrict__ b_in,
                  const float* __restrict__ b_h,
                  const float* __restrict__ W_out,
                  const float* __restrict__ b_out,
                  float* __restrict__ out)
{
    __shared__ __align__(16) _Float16 hbuf[TILE_N * HDIM]; // 64 KB

    const int tid  = threadIdx.x;
    const int row0 = blockIdx.x * TILE_N;
    const int lane = tid & 63;
    const int wave = tid >> 6;           // 0..3 = hidden-unit quarter
    const int nQ    = wave;
    const int laneM = lane & 15;
    const int quad  = lane >> 4;

    // ---------------- stage 1: Fourier features -> hbuf ----------------
    // sin(2*pi*r) = v_sin(fract(r)) : argument in revolutions.
    {
        const float2* txv = (const float2*)tx;
        const float4 Bp = *(const float4*)&Bf[4 * lane];   // freq pair
        const int f0 = 2 * lane;
        #pragma unroll 4
        for (int i = 0; i < 32; ++i) {
            const int row = wave * 32 + i;                 // 0..127
            const float2 t = txv[row0 + row];
            float r0 = t.x * Bp.x + t.y * Bp.y;            // revolutions
            float r1 = t.x * Bp.z + t.y * Bp.w;
            r0 = __builtin_amdgcn_fractf(r0);
            r1 = __builtin_amdgcn_fractf(r1);
            half2 sp = pk2(__builtin_amdgcn_sinf(r0), __builtin_amdgcn_sinf(r1));
            half2 cp = pk2(__builtin_amdgcn_cosf(r0), __builtin_amdgcn_cosf(r1));
            *(half2*)&hbuf[swz(row, f0)]         = sp;
            *(half2*)&hbuf[swz(row, f0 + NFREQ)] = cp;
        }
    }
    __syncthreads();

    // ---------------- stage 2: 8 dense layers, h in LDS, fat wave ------------
    for (int layer = 0; layer < NLAYER; ++layer) {
        const _Float16* Wl = Wall + layer * (HDIM * HDIM);
        const float*    bl = (layer == 0) ? b_in : b_h + (layer - 1) * HDIM;

        float4v acc[4][8];                 // 64 units x 128 points, one set
        #pragma unroll
        for (int at = 0; at < 4; ++at)
            #pragma unroll
            for (int pt = 0; pt < 8; ++pt)
                acc[at][pt] = (float4v){0.f, 0.f, 0.f, 0.f};

        half8 a[2][4], b[2][8];
        // preload K-step 0
        #pragma unroll
        for (int at = 0; at < 4; ++at) {
            const int o = nQ * 64 + at * 16 + laneM;
            a[0][at] = *(const half8*)&Wl[o * HDIM + quad * 8];
        }
        #pragma unroll
        for (int pt = 0; pt < 8; ++pt) {
            const int m = pt * 16 + laneM;
            b[0][pt] = *(const half8*)&hbuf[m * HDIM + ((quad ^ (m & 31)) << 3)];
        }

        #pragma unroll
        for (int ks = 0; ks < 8; ++ks) {
            const int cur = ks & 1, nxt = cur ^ 1;
            if (ks < 7) {
                const int kk = (ks + 1) * 32 + quad * 8;
                #pragma unroll
                for (int at = 0; at < 4; ++at) {
                    const int o = nQ * 64 + at * 16 + laneM;
                    a[nxt][at] = *(const half8*)&Wl[o * HDIM + kk];
                }
                #pragma unroll
                for (int pt = 0; pt < 8; ++pt) {
                    const int m = pt * 16 + laneM;
                    b[nxt][pt] = *(const half8*)&hbuf[m * HDIM + (((kk >> 3) ^ (m & 31)) << 3)];
                }
            }
            #pragma unroll
            for (int at = 0; at < 4; ++at)
                #pragma unroll
                for (int pt = 0; pt < 8; ++pt)
                    acc[at][pt] = __builtin_amdgcn_mfma_f32_16x16x32_f16(
                        a[cur][at], b[cur][pt], acc[at][pt], 0, 0, 0);
        }
        __syncthreads();   // all reads of hbuf done before overwrite

        // epilogue: fused bias+tanh, half4 writes (4 consecutive units)
        #pragma unroll
        for (int at = 0; at < 4; ++at) {
            const int u0 = nQ * 64 + at * 16 + quad * 4;
            float4 b4 = *(const float4*)&bl[u0];
            b4.x *= TANH_K; b4.y *= TANH_K; b4.z *= TANH_K; b4.w *= TANH_K;
            #pragma unroll
            for (int pt = 0; pt < 8; ++pt) {
                const int m = pt * 16 + laneM;
                const float v0 = fast_tanh_fused(acc[at][pt].x, b4.x);
                const float v1 = fast_tanh_fused(acc[at][pt].y, b4.y);
                const float v2 = fast_tanh_fused(acc[at][pt].z, b4.z);
                const float v3 = fast_tanh_fused(acc[at][pt].w, b4.w);
                const half2 lo = pk2(v0, v1);
                const half2 hi = pk2(v2, v3);
                half4 pkv;
                pkv.x = lo.x; pkv.y = lo.y; pkv.z = hi.x; pkv.w = hi.y;
                *(half4*)&hbuf[swz(m, u0)] = pkv;          // ds_write_b64
            }
        }
        __syncthreads();
    }

    // ---------------- stage 3: output matvec (b128 reads) ----------------
    {
        const int row = tid >> 1;       // 0..127
        const int kh  = tid & 1;        // half of the 32 chunks
        float sum = 0.f;
        #pragma unroll
        for (int j = 0; j < 16; ++j) {
            const int c = kh * 16 + j;
            const half8 hv = *(const half8*)&hbuf[row * HDIM + ((c ^ (row & 31)) << 3)];
            const float4 w0 = *(const float4*)&W_out[c * 8];
            const float4 w1 = *(const float4*)&W_out[c * 8 + 4];
            sum += (float)hv[0] * w0.x + (float)hv[1] * w0.y +
                   (float)hv[2] * w0.z + (float)hv[3] * w0.w +
                   (float)hv[4] * w1.x + (float)hv[5] * w1.y +
                   (float)hv[6] * w1.z + (float)hv[7] * w1.w;
        }
        sum += __shfl_xor(sum, 1);
        if (kh == 0)
            out[row0 + row] = sum + b_out[0];
    }
}

extern "C" void kernel_launch(void* const* d_in, const int* in_sizes, int n_in,
                              void* d_out, int out_size, void* d_ws, size_t ws_size,
                              hipStream_t stream) {
    const float* tx    = (const float*)d_in[0];
    const float* Bf    = (const float*)d_in[1];
    const float* W_in  = (const float*)d_in[2];
    const float* b_in  = (const float*)d_in[3];
    const float* W_h   = (const float*)d_in[4];
    const float* b_h   = (const float*)d_in[5];
    const float* W_out = (const float*)d_in[6];
    const float* b_out = (const float*)d_in[7];
    float* out = (float*)d_out;

    _Float16* Wall = (_Float16*)d_ws;   // 1 MiB scratch

    const int npts   = in_sizes[0] / 2;
    const int blocks = npts / TILE_N;   // 1024

    convert_w_kernel<<<WELTS / NTHR, NTHR, 0, stream>>>(W_in, W_h, Wall);
    ffmlp_kernel<<<blocks, NTHR, 0, stream>>>(tx, Bf, Wall, b_in, b_h,
                                              W_out, b_out, out);
}

// Round 9
// 363.867 us; speedup vs baseline: 1.2224x; 1.1690x over previous
//
#include <hip/hip_runtime.h>

// FourierFeatureMLP fused kernel for MI355X (gfx950). Round 9.
//
// r7/r8 lesson: at 8 waves/CU the unified VGPR+AGPR budget is 256/wave;
// r8's acc[4][8]+b[2][8]+a[2][4] (~290) spilled (WRITE 74MB tripwire).
// This round fits the fat wave in budget: single-buffered b[8] (32 regs),
// ping-pong a only (L2 latency is the long pole), acc[4][8] in AGPRs.
// Weight loads: per-layer base pointer + immediate offset (ks*64 B) ->
// global_load_dwordx4 with no per-step address VALU.
// Keeps r8's full-spread LDS swizzle (conflicts 1.29e7 -> 4.5e6).
//
// Layouts (MFMA 16x16x32, learn_hip-verified):
//   A: lane holds A[m=lane&15][k=quad*8+j]  -> W[o][k] row o = base+laneM
//   B: lane holds B[k=quad*8+j][n=lane&15]  -> h[pt=base+laneM][k..k+7]
//   D: n(point)=lane&15, m(unit)=quad*4+reg -> 4 consecutive units.
// Swizzle: chunk' = chunk ^ (row & 31); for the K-loop this decomposes as
// ks4 ^ quad ^ (row&31) (bit-disjoint: ks4 bits2-4, quad bits0-1).

#define HDIM   256
#define NFREQ  128
#define NLAYER 8
#define TILE_N 128         // points per block
#define NTHR   256         // 4 waves; wave = 64 units x 128 points
#define WELTS  (NLAYER * HDIM * HDIM)

typedef __attribute__((ext_vector_type(8))) _Float16 half8;
typedef __attribute__((ext_vector_type(4))) _Float16 half4;
typedef __attribute__((ext_vector_type(2))) _Float16 half2;
typedef __attribute__((ext_vector_type(4))) float float4v;

__device__ __forceinline__ half2 pk2(float a, float b) {
    return __builtin_bit_cast(half2, __builtin_amdgcn_cvt_pkrtz(a, b));
}

// tanh(acc + b) with pre-scaled bias bK = b * 2/ln2. Saturation-safe.
#define TANH_K 2.885390081777927f
__device__ __forceinline__ float fast_tanh_fused(float acc, float bK) {
    float z = __builtin_amdgcn_exp2f(fmaf(acc, TANH_K, bK));
    float r = __builtin_amdgcn_rcpf(z + 1.0f);
    return fmaf(-2.0f, r, 1.0f);
}

// swizzled LDS element index for h[row][k]
__device__ __forceinline__ int swz(int row, int k) {
    return row * HDIM + ((((k >> 3) ^ (row & 31)) << 3) | (k & 7));
}

// ---- pre-pass: fp32 -> fp16 weights into d_ws (layer 0 = W_in, 1..7 = W_h)
__global__ void convert_w_kernel(const float* __restrict__ W_in,
                                 const float* __restrict__ W_h,
                                 _Float16* __restrict__ dst)
{
    const int i = blockIdx.x * blockDim.x + threadIdx.x;
    const float v = (i < HDIM * HDIM) ? W_in[i] : W_h[i - HDIM * HDIM];
    dst[i] = (_Float16)v;
}

__global__ __launch_bounds__(NTHR, 2)
void ffmlp_kernel(const float* __restrict__ tx,
                  const float* __restrict__ Bf,
                  const _Float16* __restrict__ Wall,
                  const float* __restrict__ b_in,
                  const float* __restrict__ b_h,
                  const float* __restrict__ W_out,
                  const float* __restrict__ b_out,
                  float* __restrict__ out)
{
    __shared__ __align__(16) _Float16 hbuf[TILE_N * HDIM]; // 64 KB

    const int tid  = threadIdx.x;
    const int row0 = blockIdx.x * TILE_N;
    const int lane = tid & 63;
    const int wave = tid >> 6;           // 0..3 = hidden-unit quarter
    const int nQ    = wave;
    const int laneM = lane & 15;
    const int quad  = lane >> 4;

    // ---------------- stage 1: Fourier features -> hbuf ----------------
    {
        const float2* txv = (const float2*)tx;
        const float4 Bp = *(const float4*)&Bf[4 * lane];   // freq pair
        const int f0 = 2 * lane;
        #pragma unroll 4
        for (int i = 0; i < 32; ++i) {
            const int row = wave * 32 + i;                 // 0..127
            const float2 t = txv[row0 + row];
            float r0 = t.x * Bp.x + t.y * Bp.y;            // revolutions
            float r1 = t.x * Bp.z + t.y * Bp.w;
            r0 = __builtin_amdgcn_fractf(r0);
            r1 = __builtin_amdgcn_fractf(r1);
            half2 sp = pk2(__builtin_amdgcn_sinf(r0), __builtin_amdgcn_sinf(r1));
            half2 cp = pk2(__builtin_amdgcn_cosf(r0), __builtin_amdgcn_cosf(r1));
            *(half2*)&hbuf[swz(row, f0)]         = sp;
            *(half2*)&hbuf[swz(row, f0 + NFREQ)] = cp;
        }
    }
    __syncthreads();

    // per-wave invariants for the K loop
    // weight base: row o = nQ*64 + at*16 + laneM, element quad*8
    const _Float16* wbase = Wall + (nQ * 64 + laneM) * HDIM + quad * 8;
    // b-frag xor term per pt: t = quad ^ (m & 31), m = pt*16 + laneM
    // (= quad ^ laneM ^ ((pt&1)<<4))

    // ---------------- stage 2: 8 dense layers, h in LDS, fat wave ------------
    for (int layer = 0; layer < NLAYER; ++layer) {
        const _Float16* Wl = wbase + layer * (HDIM * HDIM);
        const float*    bl = (layer == 0) ? b_in : b_h + (layer - 1) * HDIM;

        float4v acc[4][8];                 // 64 units x 128 points (AGPRs)
        #pragma unroll
        for (int at = 0; at < 4; ++at)
            #pragma unroll
            for (int pt = 0; pt < 8; ++pt)
                acc[at][pt] = (float4v){0.f, 0.f, 0.f, 0.f};

        half8 a[2][4], b[8];
        // preload a for K-step 0 (immediate-offset loads off Wl)
        #pragma unroll
        for (int at = 0; at < 4; ++at)
            a[0][at] = *(const half8*)(Wl + at * 16 * HDIM);

        #pragma unroll
        for (int ks = 0; ks < 8; ++ks) {
            const int cur = ks & 1, nxt = cur ^ 1;
            // b-frags for this step (single-buffered; scheduler hoists)
            #pragma unroll
            for (int pt = 0; pt < 8; ++pt) {
                const int m = pt * 16 + laneM;
                const int chunk = (ks * 4) ^ quad ^ (m & 31);
                b[pt] = *(const half8*)&hbuf[m * HDIM + (chunk << 3)];
            }
            // a-frags for next step (ping-pong; hides L2 latency)
            if (ks < 7) {
                #pragma unroll
                for (int at = 0; at < 4; ++at)
                    a[nxt][at] = *(const half8*)(Wl + at * 16 * HDIM + (ks + 1) * 32);
            }
            #pragma unroll
            for (int at = 0; at < 4; ++at)
                #pragma unroll
                for (int pt = 0; pt < 8; ++pt)
                    acc[at][pt] = __builtin_amdgcn_mfma_f32_16x16x32_f16(
                        a[cur][at], b[pt], acc[at][pt], 0, 0, 0);
        }
        __syncthreads();   // all reads of hbuf done before overwrite

        // epilogue: fused bias+tanh, half4 writes (4 consecutive units)
        #pragma unroll
        for (int at = 0; at < 4; ++at) {
            const int u0 = nQ * 64 + at * 16 + quad * 4;
            float4 b4 = *(const float4*)&bl[u0];
            b4.x *= TANH_K; b4.y *= TANH_K; b4.z *= TANH_K; b4.w *= TANH_K;
            #pragma unroll
            for (int pt = 0; pt < 8; ++pt) {
                const int m = pt * 16 + laneM;
                const float v0 = fast_tanh_fused(acc[at][pt].x, b4.x);
                const float v1 = fast_tanh_fused(acc[at][pt].y, b4.y);
                const float v2 = fast_tanh_fused(acc[at][pt].z, b4.z);
                const float v3 = fast_tanh_fused(acc[at][pt].w, b4.w);
                const half2 lo = pk2(v0, v1);
                const half2 hi = pk2(v2, v3);
                half4 pkv;
                pkv.x = lo.x; pkv.y = lo.y; pkv.z = hi.x; pkv.w = hi.y;
                *(half4*)&hbuf[swz(m, u0)] = pkv;          // ds_write_b64
            }
        }
        __syncthreads();
    }

    // ---------------- stage 3: output matvec (b128 reads) ----------------
    {
        const int row = tid >> 1;       // 0..127
        const int kh  = tid & 1;        // half of the 32 chunks
        float sum = 0.f;
        #pragma unroll
        for (int j = 0; j < 16; ++j) {
            const int c = kh * 16 + j;
            const half8 hv = *(const half8*)&hbuf[row * HDIM + ((c ^ (row & 31)) << 3)];
            const float4 w0 = *(const float4*)&W_out[c * 8];
            const float4 w1 = *(const float4*)&W_out[c * 8 + 4];
            sum += (float)hv[0] * w0.x + (float)hv[1] * w0.y +
                   (float)hv[2] * w0.z + (float)hv[3] * w0.w +
                   (float)hv[4] * w1.x + (float)hv[5] * w1.y +
                   (float)hv[6] * w1.z + (float)hv[7] * w1.w;
        }
        sum += __shfl_xor(sum, 1);
        if (kh == 0)
            out[row0 + row] = sum + b_out[0];
    }
}

extern "C" void kernel_launch(void* const* d_in, const int* in_sizes, int n_in,
                              void* d_out, int out_size, void* d_ws, size_t ws_size,
                              hipStream_t stream) {
    const float* tx    = (const float*)d_in[0];
    const float* Bf    = (const float*)d_in[1];
    const float* W_in  = (const float*)d_in[2];
    const float* b_in  = (const float*)d_in[3];
    const float* W_h   = (const float*)d_in[4];
    const float* b_h   = (const float*)d_in[5];
    const float* W_out = (const float*)d_in[6];
    const float* b_out = (const float*)d_in[7];
    float* out = (float*)d_out;

    _Float16* Wall = (_Float16*)d_ws;   // 1 MiB scratch

    const int npts   = in_sizes[0] / 2;
    const int blocks = npts / TILE_N;   // 1024

    convert_w_kernel<<<WELTS / NTHR, NTHR, 0, stream>>>(W_in, W_h, Wall);
    ffmlp_kernel<<<blocks, NTHR, 0, stream>>>(tx, Bf, Wall, b_in, b_h,
                                              W_out, b_out, out);
}